// Round 7
// baseline (614.736 us; speedup 1.0000x reference)
//
#include <hip/hip_runtime.h>
#include <math.h>

// Problem constants
#define N_ROWS   131072      // 32*64*64 pixels
#define DIM      64          // embedding dim
#define KCODES   1024        // codebook entries
#define HWSZ     4096        // 64*64
#define CHW      262144      // 64*64*64 (per-batch NCHW stride)
#define OUT_ELEMS 8388608    // 32*64*64*64
#define BLOCK    256         // 4 waves/block
#define NBLOCKS  (N_ROWS / BLOCK)   // 512 blocks -> exactly 2 blocks/CU, 2 waves/SIMD

typedef float f16v __attribute__((ext_vector_type(16)));

// ---------------------------------------------------------------------------
// numpy pairwise sum of squares, n=64 (8-accumulator block, scalar order).
// Bit-exact np.sum(v**2, axis=-1); contract(off) keeps mul/add separate.
// ---------------------------------------------------------------------------
__device__ __forceinline__ float np_sumsq64(const float* v) {
#pragma clang fp contract(off)
    float r[8];
#pragma unroll
    for (int j = 0; j < 8; ++j) r[j] = v[j] * v[j];
#pragma unroll
    for (int i = 8; i < 64; i += 8) {
#pragma unroll
        for (int j = 0; j < 8; ++j) {
            float p = v[i + j] * v[i + j];
            r[j] = r[j] + p;
        }
    }
    float s01 = r[0] + r[1];
    float s23 = r[2] + r[3];
    float s45 = r[4] + r[5];
    float s67 = r[6] + r[7];
    return (s01 + s23) + (s45 + s67);
}

// ---------------------------------------------------------------------------
// Kernel 0: per-code ||w_k||^2 (numpy-pairwise) -> ws[0..1023]
// (also warms L2 with the whole codebook right before vq_main)
// ---------------------------------------------------------------------------
__global__ __launch_bounds__(256) void vq_wsum(const float* __restrict__ w,
                                               float* __restrict__ wsum) {
    int k = blockIdx.x * blockDim.x + threadIdx.x;   // grid = 4*256 = 1024
    const float* wr = w + k * DIM;
    float wv[DIM];
#pragma unroll
    for (int d = 0; d < DIM; ++d) wv[d] = wr[d];
    wsum[k] = np_sumsq64(wv);
}

// ---------------------------------------------------------------------------
// Kernel 1: main VQ — SCALAR-PATH weights, forced via inline-asm s_load.
//
//   Session law (rounds 0/3/6): any wave-wide broadcast into VGPRs pays full
//   64-lane register-fill bandwidth on the LDS/L1 return path (~1.31M cyc/CU
//   per pixel-reuse factor) — that WAS the 267 us roofline. The scalar path
//   is the only pipe not charged per-lane: v_fma_f32 v,v,s,v reads the
//   weight once from an SGPR.
//
//   Round 4 showed the compiler won't materialize weights in SGPRs on its
//   own (SGPR_Count stayed 112; buffers went to VGPRs and evicted x into
//   scratch). So we force it:
//     - s_load_dwordx16 pairs into explicit "=s" float16 registers
//     - explicit s_waitcnt lgkmcnt(0) drains, operand-chained "+s" so the
//       dependent fmas cannot be hoisted above the wait (rule #18)
//     - drain-then-issue: exactly one 32-float batch in flight, covered by
//       the 64-fma block (~128-256 cyc >= ~200 cyc L2 latency)
//   No LDS in the main loop, no barriers, no staging, no split-K.
//   P=1 pixel/thread; 512 blocks x 256 thr = 2 blocks/CU = 2 waves/SIMD;
//   the two waves' dependent fma chains interleave to saturate VALU issue.
//
//   Numerics BIT-IDENTICAL per (pixel, code) to every passing round:
//     a  = np_sumsq64(x)
//     c  = sequential __builtin_fmaf chain d=0..63 (A0,A1,B0,B1 ascending)
//     dk = fl( fl(a+b_k) - 2*c ),  argmin strict < in ascending k
// ---------------------------------------------------------------------------
__global__ __launch_bounds__(256, 2) void vq_main(const float* __restrict__ inp,
                                                  const float* __restrict__ weight,
                                                  const float* __restrict__ wsum,
                                                  float* __restrict__ out,
                                                  float* __restrict__ idx_out,
                                                  float* __restrict__ block_loss) {
    __shared__ float red[BLOCK / 64];

    const int tid = threadIdx.x;
    const int n  = blockIdx.x * BLOCK + tid;
    const int b  = n >> 12;            // n / 4096
    const int hw = n & 4095;           // n % 4096

    const float* xbase = inp + (size_t)b * CHW + hw;
    float x[DIM];
#pragma unroll
    for (int d = 0; d < DIM; ++d) x[d] = xbase[(size_t)d * HWSZ];

    const float a = np_sumsq64(x);

    float best  = 3.402823466e38f;
    int   bestk = 0;

    unsigned long long wk  = (unsigned long long)(uintptr_t)weight;  // uniform
    unsigned long long wsa = (unsigned long long)(uintptr_t)wsum;    // uniform

    f16v A0, A1, B0, B1;   // forced SGPR weight batches (s_load dest)
    float wsn;             // wsum[k], rides the LO batch

    // prologue: issue LO(0) = w[0][0..31] + wsum[0]
    asm volatile(
        "s_load_dwordx16 %0, %3, 0x0\n\t"
        "s_load_dwordx16 %1, %3, 0x40\n\t"
        "s_load_dword    %2, %4, 0x0"
        : "=s"(A0), "=s"(A1), "=s"(wsn)
        : "s"(wk), "s"(wsa));

#pragma unroll 1
    for (int k = 0; k < KCODES; ++k) {
        // complete LO(k) (+wsum[k]); "+s" chaining orders dependent fmas after
        asm volatile("s_waitcnt lgkmcnt(0)"
                     : "+s"(A0), "+s"(A1), "+s"(wsn));
        const float bsw = wsn;   // s_mov; wsn register reused by next issue

        // issue HI(k) = w[k][32..63]; in flight across the next 32 fmas
        asm volatile(
            "s_load_dwordx16 %0, %2, 0x80\n\t"
            "s_load_dwordx16 %1, %2, 0xc0"
            : "=s"(B0), "=s"(B1)
            : "s"(wk));

        float c = 0.f;
#pragma unroll
        for (int j = 0; j < 16; ++j) c = __builtin_fmaf(x[j],      A0[j], c);
#pragma unroll
        for (int j = 0; j < 16; ++j) c = __builtin_fmaf(x[16 + j], A1[j], c);

        // complete HI(k)
        asm volatile("s_waitcnt lgkmcnt(0)" : "+s"(B0), "+s"(B1));

        // advance (clamped: last iter re-issues code 1023, never OOB) and
        // issue LO(k+1) + wsum[k+1]; in flight across the next 32 fmas
        if (k < KCODES - 1) { wk += 256; wsa += 4; }
        asm volatile(
            "s_load_dwordx16 %0, %3, 0x0\n\t"
            "s_load_dwordx16 %1, %3, 0x40\n\t"
            "s_load_dword    %2, %4, 0x0"
            : "=s"(A0), "=s"(A1), "=s"(wsn)
            : "s"(wk), "s"(wsa));

#pragma unroll
        for (int j = 0; j < 16; ++j) c = __builtin_fmaf(x[32 + j], B0[j], c);
#pragma unroll
        for (int j = 0; j < 16; ++j) c = __builtin_fmaf(x[48 + j], B1[j], c);

        float dk;
        {
#pragma clang fp contract(off)
            const float s = a + bsw;
            dk = s - 2.0f * c;
        }
        if (dk < best) { best = dk; bestk = k; }
    }
    // drain the dangling prologue-for-next batch
    asm volatile("s_waitcnt lgkmcnt(0)" ::: "memory");

    // Epilogue: gather winning code row, write out (coalesced), loss partial.
    const float* wbest = weight + bestk * DIM;   // per-lane gather, L2-hot
    float* obase = out + (size_t)b * CHW + hw;
    float  ls = 0.f;
#pragma unroll
    for (int c = 0; c < DIM; ++c) {
        const float wv = wbest[c];
        obase[(size_t)c * HWSZ] = wv;
        const float df = wv - x[c];
        ls = fmaf(df, df, ls);
    }
    idx_out[n] = (float)bestk;

    // Block reduction of loss partial (4 waves of 64) — round-0 structure
#pragma unroll
    for (int off = 32; off > 0; off >>= 1) ls += __shfl_down(ls, off, 64);
    const int lane = tid & 63;
    const int wid  = tid >> 6;
    if (lane == 0) red[wid] = ls;
    __syncthreads();
    if (tid == 0)
        block_loss[blockIdx.x] = (red[0] + red[1]) + (red[2] + red[3]);
}

// ---------------------------------------------------------------------------
// Kernel 2: reduce 512 block partials -> loss scalar
//   loss = q + 0.25*e = 1.25 * mean((quantized - x)^2)
// ---------------------------------------------------------------------------
__global__ __launch_bounds__(256) void vq_loss_reduce(const float* __restrict__ bl,
                                                      float* __restrict__ loss_out) {
    double s = 0.0;
    for (int i = threadIdx.x; i < NBLOCKS; i += 256) s += (double)bl[i];
    __shared__ double red[4];
#pragma unroll
    for (int off = 32; off > 0; off >>= 1) s += __shfl_down(s, off, 64);
    const int lane = threadIdx.x & 63;
    const int wid  = threadIdx.x >> 6;
    if (lane == 0) red[wid] = s;
    __syncthreads();
    if (threadIdx.x == 0) {
        const double total = (red[0] + red[1]) + (red[2] + red[3]);
        loss_out[0] = (float)(1.25 * total / (double)OUT_ELEMS);
    }
}

// ---------------------------------------------------------------------------
extern "C" void kernel_launch(void* const* d_in, const int* in_sizes, int n_in,
                              void* d_out, int out_size, void* d_ws, size_t ws_size,
                              hipStream_t stream) {
    const float* inp    = (const float*)d_in[0];   // [32,64,64,64] NCHW fp32
    const float* weight = (const float*)d_in[1];   // [1024,64] fp32

    float* out_q    = (float*)d_out;                         // 8388608 elems
    float* out_loss = (float*)d_out + OUT_ELEMS;             // 1 elem
    float* out_idx  = (float*)d_out + OUT_ELEMS + 1;         // 131072 elems

    float* wsum       = (float*)d_ws;                        // 1024 floats
    float* block_loss = (float*)d_ws + KCODES;               // 512 floats

    vq_wsum<<<KCODES / 256, 256, 0, stream>>>(weight, wsum);
    vq_main<<<NBLOCKS, BLOCK, 0, stream>>>(inp, weight, wsum,
                                           out_q, out_idx, block_loss);
    vq_loss_reduce<<<1, 256, 0, stream>>>(block_loss, out_loss);
}

// Round 8
// 333.270 us; speedup vs baseline: 1.8446x; 1.8446x over previous
//
#include <hip/hip_runtime.h>
#include <math.h>

// Problem constants
#define N_ROWS   131072      // 32*64*64 pixels
#define DIM      64          // embedding dim
#define KCODES   1024        // codebook entries
#define HWSZ     4096        // 64*64
#define CHW      262144      // 64*64*64 (per-batch NCHW stride)
#define OUT_ELEMS 8388608    // 32*64*64*64
#define BLOCK    512         // 8 waves: halves split the codebook (split-K)
#define HALF_T   256         // threads per half
#define PIX      2           // pixels per thread: each w-broadcast feeds 2 fma chains
#define PIXBLK   (HALF_T * PIX)       // 512 pixels per block
#define NBLOCKS  (N_ROWS / PIXBLK)    // 256 -> exactly 1 block/CU, 8 waves = 2/SIMD
#define KHALF    512         // codes per half
#define TILE_K   256         // codes per LDS tile per half
#define LF4      10          // float4 per code from LDS  (dims 0..39)
#define UF4      6           // float4 per code from VMEM (dims 40..63)

// ---------------------------------------------------------------------------
// numpy pairwise sum of squares, n=64 (8-accumulator block, scalar order).
// Bit-exact np.sum(v**2, axis=-1); contract(off) keeps mul/add separate.
// ---------------------------------------------------------------------------
__device__ __forceinline__ float np_sumsq64(const float* v) {
#pragma clang fp contract(off)
    float r[8];
#pragma unroll
    for (int j = 0; j < 8; ++j) r[j] = v[j] * v[j];
#pragma unroll
    for (int i = 8; i < 64; i += 8) {
#pragma unroll
        for (int j = 0; j < 8; ++j) {
            float p = v[i + j] * v[i + j];
            r[j] = r[j] + p;
        }
    }
    float s01 = r[0] + r[1];
    float s23 = r[2] + r[3];
    float s45 = r[4] + r[5];
    float s67 = r[6] + r[7];
    return (s01 + s23) + (s45 + s67);
}

// ---------------------------------------------------------------------------
// Kernel 0: per-code ||w_k||^2 (numpy-pairwise) -> ws[0..1023]
// ---------------------------------------------------------------------------
__global__ __launch_bounds__(256) void vq_wsum(const float* __restrict__ w,
                                               float* __restrict__ wsum) {
    int k = blockIdx.x * blockDim.x + threadIdx.x;   // grid = 4*256 = 1024
    const float* wr = w + k * DIM;
    float wv[DIM];
#pragma unroll
    for (int d = 0; d < DIM; ++d) wv[d] = wr[d];
    wsum[k] = np_sumsq64(wv);
}

// ---------------------------------------------------------------------------
// fma helpers: 2 codes x 2 pixels, d-ascending (bit-identical chains).
// ---------------------------------------------------------------------------
__device__ __forceinline__ void fma16(const float4 (&r0)[4], const float4 (&r1)[4],
                                      const float* __restrict__ x0,
                                      const float* __restrict__ x1, int db,
                                      float& c00, float& c01,
                                      float& c10, float& c11) {
#pragma unroll
    for (int j = 0; j < 4; ++j) {
        const float4 va = r0[j];
        const float4 vb = r1[j];
        const int d = db + j * 4;
        c00 = __builtin_fmaf(x0[d + 0], va.x, c00); c10 = __builtin_fmaf(x1[d + 0], va.x, c10);
        c01 = __builtin_fmaf(x0[d + 0], vb.x, c01); c11 = __builtin_fmaf(x1[d + 0], vb.x, c11);
        c00 = __builtin_fmaf(x0[d + 1], va.y, c00); c10 = __builtin_fmaf(x1[d + 1], va.y, c10);
        c01 = __builtin_fmaf(x0[d + 1], vb.y, c01); c11 = __builtin_fmaf(x1[d + 1], vb.y, c11);
        c00 = __builtin_fmaf(x0[d + 2], va.z, c00); c10 = __builtin_fmaf(x1[d + 2], va.z, c10);
        c01 = __builtin_fmaf(x0[d + 2], vb.z, c01); c11 = __builtin_fmaf(x1[d + 2], vb.z, c11);
        c00 = __builtin_fmaf(x0[d + 3], va.w, c00); c10 = __builtin_fmaf(x1[d + 3], va.w, c10);
        c01 = __builtin_fmaf(x0[d + 3], vb.w, c01); c11 = __builtin_fmaf(x1[d + 3], vb.w, c11);
    }
}

__device__ __forceinline__ void fma8(const float4 (&r0)[2], const float4 (&r1)[2],
                                     const float* __restrict__ x0,
                                     const float* __restrict__ x1, int db,
                                     float& c00, float& c01,
                                     float& c10, float& c11) {
#pragma unroll
    for (int j = 0; j < 2; ++j) {
        const float4 va = r0[j];
        const float4 vb = r1[j];
        const int d = db + j * 4;
        c00 = __builtin_fmaf(x0[d + 0], va.x, c00); c10 = __builtin_fmaf(x1[d + 0], va.x, c10);
        c01 = __builtin_fmaf(x0[d + 0], vb.x, c01); c11 = __builtin_fmaf(x1[d + 0], vb.x, c11);
        c00 = __builtin_fmaf(x0[d + 1], va.y, c00); c10 = __builtin_fmaf(x1[d + 1], va.y, c10);
        c01 = __builtin_fmaf(x0[d + 1], vb.y, c01); c11 = __builtin_fmaf(x1[d + 1], vb.y, c11);
        c00 = __builtin_fmaf(x0[d + 2], va.z, c00); c10 = __builtin_fmaf(x1[d + 2], va.z, c10);
        c01 = __builtin_fmaf(x0[d + 2], vb.z, c01); c11 = __builtin_fmaf(x1[d + 2], vb.z, c11);
        c00 = __builtin_fmaf(x0[d + 3], va.w, c00); c10 = __builtin_fmaf(x1[d + 3], va.w, c10);
        c01 = __builtin_fmaf(x0[d + 3], vb.w, c01); c11 = __builtin_fmaf(x1[d + 3], vb.w, c11);
    }
}

// ---------------------------------------------------------------------------
// Kernel 1: main VQ — balanced dual-pipe weight streaming.
//   Law (r0/3/6/7): every weight-broadcast pays wave-wide register fill:
//   LDS ds_read_b128 ~10cyc, VMEM global_load_dwordx4 ~16cyc (L1/L2-hot),
//   SMEM unpipelineable (r7). The two vector pipes (lgkm/vm) overlap (r6).
//   Round 6 split 32/32 -> slow pipe carried 2048 cyc/CU-body vs 1280.
//   Here: 40 dims LDS (20 reads -> 1600 cyc/CU-body) + 24 dims VMEM
//   (12 loads -> 1536 cyc/CU-body), U-loads issued ONE CODE-PAIR AHEAD
//   (consume-then-issue: ~500cyc in-flight cover vs r6's same-body tail).
//   Model floor ~171 us. Everything else = round-3/6 verbatim.
//   Numerics BIT-IDENTICAL per (pixel, code):
//     a  = np_sumsq64(x);  c = sequential fmaf chain d=0..63
//     (dims 0-39 via LDS regs, 40-63 via VMEM regs, consumed ascending)
//     dk = fl( fl(a+b_k) - 2*c ),  argmin strict < (ascending code order)
// ---------------------------------------------------------------------------
__global__ __launch_bounds__(512, 2) void vq_main(const float* __restrict__ inp,
                                                  const float* __restrict__ weight,
                                                  const float* __restrict__ wsum,
                                                  float* __restrict__ out,
                                                  float* __restrict__ idx_out,
                                                  float* __restrict__ block_loss) {
    __shared__ float sw[2][TILE_K * (LF4 * 4)];  // 2 x 40 KB: dims 0..39
    __shared__ float sws[2][TILE_K];             // wsum tiles
    __shared__ float cbv[2][HALF_T];             // lower half's best values
    __shared__ int   cbk[2][HALF_T];             // lower half's best indices
    __shared__ float red[BLOCK / 64];
    __shared__ unsigned long long wop;           // laundered weight base ptr

    const int tid  = threadIdx.x;
    const int half = tid >> 8;        // 0 = codes 0..511, 1 = codes 512..1023
    const int t    = tid & 255;
    const int n0   = blockIdx.x * PIXBLK + t;
    const int n1   = n0 + HALF_T;
    const int b0 = n0 >> 12, hw0 = n0 & 4095;
    const int b1 = n1 >> 12, hw1 = n1 & 4095;

    if (tid == 0) wop = (unsigned long long)(uintptr_t)weight;

    const float* xb0 = inp + (size_t)b0 * CHW + hw0;
    const float* xb1 = inp + (size_t)b1 * CHW + hw1;
    float x0[DIM], x1[DIM];
#pragma unroll
    for (int d = 0; d < DIM; ++d) x0[d] = xb0[(size_t)d * HWSZ];
#pragma unroll
    for (int d = 0; d < DIM; ++d) x1[d] = xb1[(size_t)d * HWSZ];

    const float a0 = np_sumsq64(x0);
    const float a1 = np_sumsq64(x1);

    float best0 = 3.402823466e38f, best1 = 3.402823466e38f;
    int   bk0 = 0, bk1 = 0;

    const int kbase = half * KHALF;
    const int lastE = kbase + KHALF - 2;   // last even code of this half

    __syncthreads();                                   // publish wop
    const float4* wf4 = (const float4*)(uintptr_t)wop; // opaque -> VMEM path

    for (int tile = 0; tile < KHALF; tile += TILE_K) {
        // ---- stage dims 0..39 of 256 codes: thread t stages code t ----
        __syncthreads();   // protect previous tile's readers (both halves)
        {
            const float4* gsrc = (const float4*)(weight + (size_t)(kbase + tile) * DIM);
            float4* ldst = (float4*)(&sw[half][0]);
#pragma unroll
            for (int j = 0; j < LF4; ++j)
                ldst[t * LF4 + j] = gsrc[t * 16 + j];
            sws[half][t] = wsum[kbase + tile + t];
        }
        __syncthreads();

        const float4* swv = (const float4*)(&sw[half][0]);

        // prologue: issue U(code0), U(code1) of this tile (dims 40..63)
        float4 UAh[4], UAt[2], UBh[4], UBt[2];
        {
            const float4* pe = wf4 + ((size_t)(kbase + tile) << 4) + LF4;
            const float4* po = pe + 16;
#pragma unroll
            for (int j = 0; j < 4; ++j) { UAh[j] = pe[j]; UBh[j] = po[j]; }
#pragma unroll
            for (int j = 0; j < 2; ++j) { UAt[j] = pe[4 + j]; UBt[j] = po[4 + j]; }
        }

#pragma unroll 1
        for (int kk = 0; kk < TILE_K; kk += 2) {
            const float bsw0 = sws[half][kk];
            const float bsw1 = sws[half][kk + 1];
            float c00 = 0.f, c01 = 0.f, c10 = 0.f, c11 = 0.f;

            // dims 0..15 (LDS broadcast)
            {
                float4 L0[4], L1[4];
#pragma unroll
                for (int j = 0; j < 4; ++j) {
                    L0[j] = swv[kk * LF4 + j];
                    L1[j] = swv[(kk + 1) * LF4 + j];
                }
                fma16(L0, L1, x0, x1, 0, c00, c01, c10, c11);
            }
            // dims 16..31 (LDS)
            {
                float4 L0[4], L1[4];
#pragma unroll
                for (int j = 0; j < 4; ++j) {
                    L0[j] = swv[kk * LF4 + 4 + j];
                    L1[j] = swv[(kk + 1) * LF4 + 4 + j];
                }
                fma16(L0, L1, x0, x1, 16, c00, c01, c10, c11);
            }
            // dims 32..39 (LDS)
            {
                float4 M0[2], M1[2];
#pragma unroll
                for (int j = 0; j < 2; ++j) {
                    M0[j] = swv[kk * LF4 + 8 + j];
                    M1[j] = swv[(kk + 1) * LF4 + 8 + j];
                }
                fma8(M0, M1, x0, x1, 32, c00, c01, c10, c11);
            }
            // dims 40..63 (VMEM regs, issued one pair ago)
            fma16(UAh, UBh, x0, x1, 40, c00, c01, c10, c11);
            fma8(UAt, UBt, x0, x1, 56, c00, c01, c10, c11);

            // issue next pair's U loads (clamped; WAR on regs is safe)
            {
                const int ge = kbase + tile + kk + 2;
                const int gc = (ge <= lastE) ? ge : lastE;
                const float4* pe = wf4 + ((size_t)gc << 4) + LF4;
                const float4* po = pe + 16;
#pragma unroll
                for (int j = 0; j < 4; ++j) { UAh[j] = pe[j]; UBh[j] = po[j]; }
#pragma unroll
                for (int j = 0; j < 2; ++j) { UAt[j] = pe[4 + j]; UBt[j] = po[4 + j]; }
            }

            float dk00, dk01, dk10, dk11;
            {
#pragma clang fp contract(off)
                const float sa = a0 + bsw0;
                const float sb = a0 + bsw1;
                const float ta = a1 + bsw0;
                const float tb = a1 + bsw1;
                dk00 = sa - 2.0f * c00;
                dk01 = sb - 2.0f * c01;
                dk10 = ta - 2.0f * c10;
                dk11 = tb - 2.0f * c11;
            }
            const int k0 = kbase + tile + kk;
            if (dk00 < best0) { best0 = dk00; bk0 = k0; }
            if (dk01 < best0) { best0 = dk01; bk0 = k0 + 1; }
            if (dk10 < best1) { best1 = dk10; bk1 = k0; }
            if (dk11 < best1) { best1 = dk11; bk1 = k0 + 1; }
        }
    }

    // ---- combine halves: lower publishes, upper resolves ----
    __syncthreads();
    if (half == 0) {
        cbv[0][t] = best0; cbk[0][t] = bk0;
        cbv[1][t] = best1; cbk[1][t] = bk1;
    }
    __syncthreads();

    float ls = 0.f;
    if (half == 1) {
        // upper wins only if strictly smaller (lower indices take ties)
        const float lo0 = cbv[0][t]; const int lk0 = cbk[0][t];
        const float lo1 = cbv[1][t]; const int lk1 = cbk[1][t];
        if (!(best0 < lo0)) { best0 = lo0; bk0 = lk0; }
        if (!(best1 < lo1)) { best1 = lo1; bk1 = lk1; }

        // Epilogue: gather winning code rows, write out, loss partials.
        const float* wb0 = weight + bk0 * DIM;   // per-lane gather, L2-hot
        const float* wb1 = weight + bk1 * DIM;
        float* ob0 = out + (size_t)b0 * CHW + hw0;
        float* ob1 = out + (size_t)b1 * CHW + hw1;
#pragma unroll
        for (int c = 0; c < DIM; ++c) {
            const float wv0 = wb0[c];
            ob0[(size_t)c * HWSZ] = wv0;
            const float d0 = wv0 - x0[c];
            ls = fmaf(d0, d0, ls);
            const float wv1 = wb1[c];
            ob1[(size_t)c * HWSZ] = wv1;
            const float d1 = wv1 - x1[c];
            ls = fmaf(d1, d1, ls);
        }
        idx_out[n0] = (float)bk0;
        idx_out[n1] = (float)bk1;
    }

    // Block reduction of loss partial (8 waves; lower waves contribute 0)
#pragma unroll
    for (int off = 32; off > 0; off >>= 1) ls += __shfl_down(ls, off, 64);
    const int lane = tid & 63;
    const int wid  = tid >> 6;
    if (lane == 0) red[wid] = ls;
    __syncthreads();
    if (tid == 0) {
        float s = 0.f;
#pragma unroll
        for (int w = 0; w < BLOCK / 64; ++w) s += red[w];
        block_loss[blockIdx.x] = s;
    }
}

// ---------------------------------------------------------------------------
// Kernel 2: reduce 256 block partials -> loss scalar
//   loss = q + 0.25*e = 1.25 * mean((quantized - x)^2)
// ---------------------------------------------------------------------------
__global__ __launch_bounds__(256) void vq_loss_reduce(const float* __restrict__ bl,
                                                      float* __restrict__ loss_out) {
    double s = 0.0;
    for (int i = threadIdx.x; i < NBLOCKS; i += 256) s += (double)bl[i];
    __shared__ double red[4];
#pragma unroll
    for (int off = 32; off > 0; off >>= 1) s += __shfl_down(s, off, 64);
    const int lane = threadIdx.x & 63;
    const int wid  = threadIdx.x >> 6;
    if (lane == 0) red[wid] = s;
    __syncthreads();
    if (threadIdx.x == 0) {
        const double total = (red[0] + red[1]) + (red[2] + red[3]);
        loss_out[0] = (float)(1.25 * total / (double)OUT_ELEMS);
    }
}

// ---------------------------------------------------------------------------
extern "C" void kernel_launch(void* const* d_in, const int* in_sizes, int n_in,
                              void* d_out, int out_size, void* d_ws, size_t ws_size,
                              hipStream_t stream) {
    const float* inp    = (const float*)d_in[0];   // [32,64,64,64] NCHW fp32
    const float* weight = (const float*)d_in[1];   // [1024,64] fp32

    float* out_q    = (float*)d_out;                         // 8388608 elems
    float* out_loss = (float*)d_out + OUT_ELEMS;             // 1 elem
    float* out_idx  = (float*)d_out + OUT_ELEMS + 1;         // 131072 elems

    float* wsum       = (float*)d_ws;                        // 1024 floats
    float* block_loss = (float*)d_ws + KCODES;               // 256 floats

    vq_wsum<<<KCODES / 256, 256, 0, stream>>>(weight, wsum);
    vq_main<<<NBLOCKS, BLOCK, 0, stream>>>(inp, weight, wsum,
                                           out_q, out_idx, block_loss);
    vq_loss_reduce<<<1, 256, 0, stream>>>(block_loss, out_loss);
}